// Round 9
// baseline (108.896 us; speedup 1.0000x reference)
//
#include <hip/hip_runtime.h>
#include <hip/hip_bf16.h>

typedef short bf16x8 __attribute__((ext_vector_type(8)));
typedef float f32x4 __attribute__((ext_vector_type(4)));
typedef unsigned int u32;
typedef u32 u32x4 __attribute__((ext_vector_type(4)));

#define T_SEQ 2048
#define NB 8
#define NEGB (-1e30f)

__device__ inline unsigned short f2bf(float f) {
  unsigned u = __builtin_bit_cast(unsigned, f);
  u += 0x7FFFu + ((u >> 16) & 1u);   // round-to-nearest-even
  return (unsigned short)(u >> 16);
}
__device__ inline float bf2f(unsigned short h) {
  unsigned u = ((unsigned)h) << 16;
  return __builtin_bit_cast(float, u);
}
__device__ inline u32 cvt2(float a, float b) {  // v_cvt_pk_bf16_f32 via HIP
  __hip_bfloat162 h = __float22bfloat162_rn(make_float2(a, b));
  u32 r;
  __builtin_memcpy(&r, &h, 4);
  return r;
}
__device__ inline bf16x8 pack8(float4 a, float4 b) {
  u32x4 p;
  p[0] = cvt2(a.x, a.y);
  p[1] = cvt2(a.z, a.w);
  p[2] = cvt2(b.x, b.y);
  p[3] = cvt2(b.z, b.w);
  return __builtin_bit_cast(bf16x8, p);
}
__device__ inline f32x4 mfma16(bf16x8 a, bf16x8 b, f32x4 c) {
  return __builtin_amdgcn_mfma_f32_16x16x32_bf16(a, b, c, 0, 0, 0);
}

// ---- pad_mask dtype detection: bool(1B) vs int32(4B) storage -------------
__global__ void detect_k(const unsigned char* m, int* flag) {
  __shared__ int ones, bad;
  int tid = threadIdx.x;
  if (tid == 0) { ones = 0; bad = 0; }
  __syncthreads();
  int lo = 0, lb = 0;
  for (int i = tid; i < NB * T_SEQ; i += 256) {
    int v = (m[i] != 0);
    lo += v;
    if (i & 3) lb += v;
  }
  atomicAdd(&ones, lo);
  atomicAdd(&bad, lb);
  __syncthreads();
  if (tid == 0) *flag = (ones > 0 && bad == 0) ? 1 : 0;
}

__global__ void lengths_k(const unsigned char* m, const int* flag, int* lengths) {
  int b = blockIdx.x, tid = threadIdx.x;
  int cnt = 0;
  if (*flag) {
    const int* mi = (const int*)m;
    for (int t = tid; t < T_SEQ; t += 256) cnt += (mi[b * T_SEQ + t] == 0);
  } else {
    for (int t = tid; t < T_SEQ; t += 256) cnt += (m[b * T_SEQ + t] == 0);
  }
  for (int off = 32; off >= 1; off >>= 1) cnt += __shfl_xor(cnt, off);
  __shared__ int wsum[4];
  if ((tid & 63) == 0) wsum[tid >> 6] = cnt;
  __syncthreads();
  if (tid == 0) lengths[b] = wsum[0] + wsum[1] + wsum[2] + wsum[3];
}

// Frag-ordered WT: wt2[mi][ks(32)][nt(4)][lane(64)][i(8)] (bf16)
//   element = W_mi[k = ks*32 + (lane>>4)*8 + i][n = nt*16 + (lane&15)]
// -> a W-frag load is one PERFECT ascending 1KB instruction.
__global__ void wt_k(const float* Wq, const float* Wk, const float* Wv,
                     unsigned short* wt) {
  int e = blockIdx.x * 256 + threadIdx.x;
  if (e >= 3 * 65536) return;
  int i = e & 7;
  int lane = (e >> 3) & 63;
  int nt = (e >> 9) & 3;
  int ks = (e >> 11) & 31;
  int mi = e >> 16;
  int kk = ks * 32 + (lane >> 4) * 8 + i;
  int n = nt * 16 + (lane & 15);
  const float* W = (mi == 0) ? Wq : (mi == 1) ? Wk : Wv;
  wt[e] = f2bf(W[kk * 64 + n]);
}

// Projection GEMM v8: copy-shaped streaming (m13 regime).
// Block = 64 rows; whole 64x512 half-K panel staged as bf16 in 64KB LDS.
// Each wave streams 8 WHOLE rows: 2 ascending float4 loads per row (2KB
// contiguous span) -> cvt_pk -> one swizzled ds_write_b128. 3 barriers
// TOTAL per block. MFMA phase barrier-free; W-frags = ascending 1KB loads.
__global__ __launch_bounds__(512, 4) void proj_k(
    const float* Q, const float* K, const float* V, const unsigned short* wt2,
    unsigned short* qo, unsigned short* ko, unsigned short* vTb) {
  __shared__ unsigned short xls[64 * 512];  // 64KB: [row][k-half] bf16, swizzled
  int mi = blockIdx.y;
  const float* X = (mi == 0) ? Q : (mi == 1) ? K : V;
  const unsigned short* wtm = wt2 + mi * 65536;
  int tid = threadIdx.x;
  int w = tid >> 6, lane = tid & 63, l15 = lane & 15, g = lane >> 4;
  int wr = w >> 1, wc = w & 1;
  int r0b = blockIdx.x * 64;

  f32x4 acc[2];
  acc[0] = 0; acc[1] = 0;

  int arow = wr * 16 + l15;
  // A-frag LDS byte base: row*1024 + (nominal k-byte ^ ((row&7)<<4))
  char* aldsrow = (char*)xls + arow * 1024;
  int asw = (l15 & 7) << 4;

#pragma unroll
  for (int h = 0; h < 2; ++h) {
    int k0 = h * 512;
    // ---- stage: 8 whole rows per wave, ascending contiguous loads ----
#pragma unroll
    for (int batch = 0; batch < 2; ++batch) {
      float4 fa[4], fb[4];
#pragma unroll
      for (int i = 0; i < 4; ++i) {
        int r = w * 8 + batch * 4 + i;
        const float4* src = (const float4*)(X + (size_t)(r0b + r) * 1024 + k0);
        fa[i] = src[2 * lane];      // k-local 8*lane .. +3
        fb[i] = src[2 * lane + 1];  // k-local 8*lane+4 .. +7
      }
#pragma unroll
      for (int i = 0; i < 4; ++i) {
        int r = w * 8 + batch * 4 + i;
        int sw = (r & 7) << 4;
        *(bf16x8*)((char*)xls + r * 1024 + ((16 * lane) ^ sw)) =
            pack8(fa[i], fb[i]);
      }
    }
    __syncthreads();  // panel ready (1 barrier)

    // ---- compute: 16 k-subtiles, barrier-free straight line ----
#pragma unroll 4
    for (int ks = 0; ks < 16; ++ks) {
      bf16x8 a = *(const bf16x8*)(aldsrow + ((ks * 64 + g * 16) ^ asw));
      int ksg = h * 16 + ks;
      const bf16x8* wbase =
          (const bf16x8*)(wtm + (size_t)ksg * 2048 + (wc * 2) * 512 + lane * 8);
      bf16x8 w0 = wbase[0];
      bf16x8 w1 = wbase[64];  // nt+1: +512 bf16
      acc[0] = mfma16(a, w0, acc[0]);
      acc[1] = mfma16(a, w1, acc[1]);
    }
    if (h == 0) __syncthreads();  // protect LDS overwrite (1 barrier)
  }

  // D layout: col = lane&15, row = g*4 + vv; wave owns 16x32 tile directly
#pragma unroll
  for (int nt = 0; nt < 2; ++nt)
#pragma unroll
    for (int vv = 0; vv < 4; ++vv) {
      int rr = r0b + wr * 16 + g * 4 + vv;
      int c = wc * 32 + nt * 16 + l15;
      float val = acc[nt][vv];
      if (mi == 0) {
        qo[(size_t)rr * 64 + c] = f2bf(val * 0.03125f);  // fold C^-0.5
      } else if (mi == 1) {
        ko[(size_t)rr * 64 + c] = f2bf(val);
      } else {
        int bb = rr >> 11, ts = rr & 2047;
        // tile-blocked vT: [b][t/32][d][t%32]
        vTb[(((size_t)bb * 64 + (ts >> 5)) * 64 + c) * 32 + (ts & 31)] =
            f2bf(val);
      }
    }
}

// vmean[b][d] from tile-blocked vT
__global__ void vmean_k(const unsigned short* vTb, float* vmean) {
  int b = blockIdx.x, tid = threadIdx.x;
  int k8 = tid & 3;
  int d = tid >> 2;
  const unsigned short* base = vTb + (size_t)b * 131072;
  float s = 0.f;
  for (int tt = 0; tt < 64; ++tt) {
    bf16x8 v = *(const bf16x8*)&base[(tt * 64 + d) * 32 + k8 * 8];
#pragma unroll
    for (int i = 0; i < 8; ++i) s += bf2f((unsigned short)v[i]);
  }
  s += __shfl_xor(s, 1);
  s += __shfl_xor(s, 2);
  if (k8 == 0) vmean[b * 64 + d] = s * (1.0f / T_SEQ);
}

// Flash attention: 512 threads = 8 waves = 4 key-chunks x 2 row-groups;
// 32 q-rows per block; 512 blocks (2/CU) with work-complementary swizzle.
__global__ __launch_bounds__(512, 4) void attn_k(
    const unsigned short* q, const unsigned short* k, const unsigned short* vTb,
    const float* vmean, const int* lengths, float* Out) {
  __shared__ unsigned short pL[8][16][40];      // per-wave P round-trip
  __shared__ unsigned short oP[4][2][16][64];   // bf16 partial O [j][r][row][col]
  __shared__ float mP[4][2][16], lP[4][2][16];

  // complementary work pairing: co-resident blocks sum to ~constant work
  int id = blockIdx.x;
  int raw = id & 63, b = id >> 6;
  int xx = (raw + 8 * b) & 63;
  int tile = (xx < 32) ? xx : 95 - xx;   // bijective on 0..63
  int t0 = tile * 32;

  int tid = threadIdx.x;
  int w = tid >> 6, lane = tid & 63;
  int j = w >> 1, r = w & 1;
  int l15 = lane & 15, g = lane >> 4;
  int t_base = t0 + r * 16;

  const bf16x8* qrow =
      (const bf16x8*)(q + ((size_t)b * T_SEQ + t_base + l15) * 64);
  bf16x8 aq0 = qrow[g];
  bf16x8 aq1 = qrow[4 + g];

  f32x4 o[4];
  float m[4], l[4];
#pragma unroll
  for (int i = 0; i < 4; ++i) { o[i] = 0; m[i] = NEGB; l[i] = 0.f; }

  const bf16x8* kch = (const bf16x8*)k + (size_t)b * T_SEQ * 8;
  const unsigned short* vch = vTb + (size_t)b * 131072;

  // balanced contiguous tile-chunks over this block's NT key-tiles
  int NT = tile + 1;
  int qn = NT >> 2, rem = NT & 3;
  int start = j * qn + (j < rem ? j : rem);
  int end = start + qn + (j < rem ? 1 : 0);
  int capw = ((t_base + 15) >> 5) + 1;
  if (end > capw) end = capw;

  for (int tt = start; tt < end; ++tt) {
    int s0 = tt * 32;
    f32x4 sa0, sa1;
    sa0 = 0; sa1 = 0;
    bf16x8 kb00 = kch[(size_t)(s0 + l15) * 8 + g];
    bf16x8 kb01 = kch[(size_t)(s0 + l15) * 8 + 4 + g];
    bf16x8 kb10 = kch[(size_t)(s0 + 16 + l15) * 8 + g];
    bf16x8 kb11 = kch[(size_t)(s0 + 16 + l15) * 8 + 4 + g];
    sa0 = mfma16(aq0, kb00, sa0);
    sa0 = mfma16(aq1, kb01, sa0);
    sa1 = mfma16(aq0, kb10, sa1);
    sa1 = mfma16(aq1, kb11, sa1);
#pragma unroll
    for (int vv = 0; vv < 4; ++vv) {
      int t = t_base + g * 4 + vv;
      float v0 = (s0 + l15 <= t) ? sa0[vv] : NEGB;
      float v1 = (s0 + 16 + l15 <= t) ? sa1[vv] : NEGB;
      float rm = fmaxf(v0, v1);
#pragma unroll
      for (int off = 8; off >= 1; off >>= 1)
        rm = fmaxf(rm, __shfl_xor(rm, off));
      float mn = fmaxf(m[vv], rm);
      float corr = __expf(m[vv] - mn);
      float p0 = (v0 == NEGB) ? 0.f : __expf(v0 - mn);  // all-masked tile guard
      float p1 = (v1 == NEGB) ? 0.f : __expf(v1 - mn);
      float rs = p0 + p1;
#pragma unroll
      for (int off = 8; off >= 1; off >>= 1) rs += __shfl_xor(rs, off);
      l[vv] = l[vv] * corr + rs;
      m[vv] = mn;
#pragma unroll
      for (int nt = 0; nt < 4; ++nt) o[nt][vv] *= corr;
      pL[w][g * 4 + vv][l15] = f2bf(p0);
      pL[w][g * 4 + vv][16 + l15] = f2bf(p1);
    }
    bf16x8 ap = *(const bf16x8*)&pL[w][l15][g * 8];
#pragma unroll
    for (int nt = 0; nt < 4; ++nt) {
      bf16x8 bv =
          *(const bf16x8*)&vch[((size_t)(tt * 64 + nt * 16 + l15)) * 32 + g * 8];
      o[nt] = mfma16(ap, bv, o[nt]);
    }
  }

  __syncthreads();
#pragma unroll
  for (int nt = 0; nt < 4; ++nt)
#pragma unroll
    for (int vv = 0; vv < 4; ++vv)
      oP[j][r][g * 4 + vv][nt * 16 + l15] = f2bf(o[nt][vv]);
  if (l15 == 0) {
#pragma unroll
    for (int vv = 0; vv < 4; ++vv) {
      mP[j][r][g * 4 + vv] = m[vv];
      lP[j][r][g * 4 + vv] = l[vv];
    }
  }
  __syncthreads();

  if (w < 2) {  // merge wave r=w: 16 rows x 64 cols, 4-way j-merge
    int len = lengths[b];
#pragma unroll 4
    for (int row = 0; row < 16; ++row) {
      float m0 = mP[0][w][row], m1 = mP[1][w][row];
      float m2 = mP[2][w][row], m3 = mP[3][w][row];
      float ms = fmaxf(fmaxf(m0, m1), fmaxf(m2, m3));
      float e0 = __expf(m0 - ms), e1 = __expf(m1 - ms);
      float e2 = __expf(m2 - ms), e3 = __expf(m3 - ms);
      float ls = lP[0][w][row] * e0 + lP[1][w][row] * e1 +
                 lP[2][w][row] * e2 + lP[3][w][row] * e3;
      float ov = bf2f(oP[0][w][row][lane]) * e0 +
                 bf2f(oP[1][w][row][lane]) * e1 +
                 bf2f(oP[2][w][row][lane]) * e2 +
                 bf2f(oP[3][w][row][lane]) * e3;
      float val = ov / ls;
      int t = t0 + w * 16 + row;
      if (t >= len) val = vmean[b * 64 + lane];  // padded query row -> mean(v)
      Out[((size_t)b * T_SEQ + t) * 64 + lane] = val;
    }
  }
}

extern "C" void kernel_launch(void* const* d_in, const int* in_sizes, int n_in,
                              void* d_out, int out_size, void* d_ws,
                              size_t ws_size, hipStream_t stream) {
  const float* V = (const float*)d_in[0];
  const float* K = (const float*)d_in[1];
  const float* Q = (const float*)d_in[2];
  const float* Wq = (const float*)d_in[3];
  const float* Wk = (const float*)d_in[4];
  const float* Wv = (const float*)d_in[5];
  const unsigned char* mask = (const unsigned char*)d_in[6];
  float* O = (float*)d_out;
  char* ws = (char*)d_ws;

  unsigned short* wt = (unsigned short*)(ws);                        // 384 KiB
  unsigned short* qb = (unsigned short*)(ws + 393216);               // 2 MiB
  unsigned short* kb = (unsigned short*)(ws + 393216 + 2097152);     // 2 MiB
  unsigned short* vTb = (unsigned short*)(ws + 393216 + 2 * 2097152);// 2 MiB
  float* vmean = (float*)(ws + 393216 + 3 * 2097152);                // 2 KiB
  int* lengths = (int*)(ws + 393216 + 3 * 2097152 + 2048);
  int* flag = lengths + 8;

  detect_k<<<1, 256, 0, stream>>>(mask, flag);
  lengths_k<<<NB, 256, 0, stream>>>(mask, flag, lengths);
  wt_k<<<768, 256, 0, stream>>>(Wq, Wk, Wv, wt);
  proj_k<<<dim3(256, 3), 512, 0, stream>>>(Q, K, V, wt, qb, kb, vTb);
  vmean_k<<<NB, 256, 0, stream>>>(vTb, vmean);
  attn_k<<<512, 512, 0, stream>>>(qb, kb, vTb, vmean, lengths, O);
}

// Round 10
// 89.993 us; speedup vs baseline: 1.2101x; 1.2101x over previous
//
#include <hip/hip_runtime.h>
#include <hip/hip_bf16.h>

typedef short bf16x8 __attribute__((ext_vector_type(8)));
typedef float f32x4 __attribute__((ext_vector_type(4)));
typedef unsigned int u32;
typedef u32 u32x4 __attribute__((ext_vector_type(4)));

#define T_SEQ 2048
#define NB 8
#define NEGB (-1e30f)

__device__ inline unsigned short f2bf(float f) {
  unsigned u = __builtin_bit_cast(unsigned, f);
  u += 0x7FFFu + ((u >> 16) & 1u);   // round-to-nearest-even
  return (unsigned short)(u >> 16);
}
__device__ inline float bf2f(unsigned short h) {
  unsigned u = ((unsigned)h) << 16;
  return __builtin_bit_cast(float, u);
}
__device__ inline u32 cvt2(float a, float b) {  // v_cvt_pk_bf16_f32 via HIP
  __hip_bfloat162 h = __float22bfloat162_rn(make_float2(a, b));
  u32 r;
  __builtin_memcpy(&r, &h, 4);
  return r;
}
__device__ inline bf16x8 pack8(float4 a, float4 b) {
  u32x4 p;
  p[0] = cvt2(a.x, a.y);
  p[1] = cvt2(a.z, a.w);
  p[2] = cvt2(b.x, b.y);
  p[3] = cvt2(b.z, b.w);
  return __builtin_bit_cast(bf16x8, p);
}
__device__ inline f32x4 mfma16(bf16x8 a, bf16x8 b, f32x4 c) {
  return __builtin_amdgcn_mfma_f32_16x16x32_bf16(a, b, c, 0, 0, 0);
}
// async 16B global -> LDS (DMA). ldsptr wave-uniform; lane l lands at +l*16.
__device__ __forceinline__ void gl_lds16(const void* g, void* l) {
  __builtin_amdgcn_global_load_lds(
      (const __attribute__((address_space(1))) void*)g,
      (__attribute__((address_space(3))) void*)l, 16, 0, 0);
}

// ---- meta: pad_mask dtype detect (redundant per block) + lengths ----------
// int32 0/1 storage has 1-bytes ONLY at byte%4==0; bool padding always has a
// misaligned 1 (tail byte 2047). ones==0 -> interps agree anyway.
__global__ void meta_k(const unsigned char* m, int* lengths) {
  int b = blockIdx.x, tid = threadIdx.x;
  int lo = 0, lb = 0;
  for (int i = tid; i < NB * T_SEQ; i += 256) {
    int v = (m[i] != 0);
    lo += v;
    if (i & 3) lb += v;
  }
  for (int off = 32; off >= 1; off >>= 1) {
    lo += __shfl_xor(lo, off);
    lb += __shfl_xor(lb, off);
  }
  __shared__ int s0[4], s1[4], ws2[4];
  if ((tid & 63) == 0) { s0[tid >> 6] = lo; s1[tid >> 6] = lb; }
  __syncthreads();
  int ones = s0[0] + s0[1] + s0[2] + s0[3];
  int bad = s1[0] + s1[1] + s1[2] + s1[3];
  int flag = (ones > 0 && bad == 0);  // 1 => int32 storage
  int cnt = 0;
  if (flag) {
    const int* mi = (const int*)m;
    for (int t = tid; t < T_SEQ; t += 256) cnt += (mi[b * T_SEQ + t] == 0);
  } else {
    for (int t = tid; t < T_SEQ; t += 256) cnt += (m[b * T_SEQ + t] == 0);
  }
  for (int off = 32; off >= 1; off >>= 1) cnt += __shfl_xor(cnt, off);
  __syncthreads();
  if ((tid & 63) == 0) ws2[tid >> 6] = cnt;
  __syncthreads();
  if (tid == 0) lengths[b] = ws2[0] + ws2[1] + ws2[2] + ws2[3];
}

// WT[mi][n][k] (bf16) = W_mi[k][n]
__global__ void wt_k(const float* Wq, const float* Wk, const float* Wv,
                     unsigned short* wt) {
  int e = blockIdx.x * 256 + threadIdx.x;
  if (e >= 3 * 64 * 1024) return;
  int mi = e >> 16;
  int rem = e & 65535;
  int kk = rem & 1023, n = rem >> 10;
  const float* W = (mi == 0) ? Wq : (mi == 1) ? Wk : Wv;
  wt[e] = f2bf(W[kk * 64 + n]);
}

// Projection GEMM (R6-proven, AT PLATFORM WALL ~78us — do not restructure):
// double-buffer DMA staging, counted vmcnt(3), raw barriers.
// Added: mi==2 blocks LDS-reduce V column sums -> atomicAdd vmsum[b][d]
// (replaces the separate vmean kernel).
__global__ __launch_bounds__(512, 4) void proj_k(
    const float* Q, const float* K, const float* V, const unsigned short* wt,
    unsigned short* qo, unsigned short* ko, unsigned short* vTb, float* vmsum) {
  __shared__ float xs[2][4096];          // 16 KB x2: [row][k] f32 (pre-swizzled)
  __shared__ unsigned short wss[2][4096];// 8 KB x2: [n][k] bf16 (pre-swizzled)
  int mi = blockIdx.y;
  const float* X = (mi == 0) ? Q : (mi == 1) ? K : V;
  const unsigned short* wtm = wt + mi * 65536;
  int tid = threadIdx.x;
  int w = tid >> 6, lane = tid & 63, l15 = lane & 15, g = lane >> 4;
  int wr = w >> 1, wc = w & 1;
  int r0b = blockIdx.x * 64;

  // staging addresses: per wave exactly 3 gl_lds instrs/chunk
  int segA = w * 2;
  int rowA0 = segA * 4 + (lane >> 4);
  int rowA1 = rowA0 + 4;
  int colA0 = ((lane & 15) ^ (rowA0 & 15)) * 4;
  int colA1 = ((lane & 15) ^ (rowA1 & 15)) * 4;
  const float* srcA0 = X + (size_t)(r0b + rowA0) * 1024 + colA0;
  const float* srcA1 = X + (size_t)(r0b + rowA1) * 1024 + colA1;
  int nW = w * 8 + (lane >> 3);
  int skW = ((lane & 7) ^ (nW & 7)) * 8;
  const unsigned short* srcW = wtm + (size_t)nW * 1024 + skW;

  f32x4 acc[2];
  acc[0] = 0; acc[1] = 0;

#define STAGE(buf, kc2)                                          \
  do {                                                           \
    gl_lds16(srcA0 + (kc2) * 64, &xs[buf][segA * 256]);          \
    gl_lds16(srcA1 + (kc2) * 64, &xs[buf][segA * 256 + 256]);    \
    gl_lds16(srcW + (kc2) * 64, &wss[buf][w * 512]);             \
  } while (0)

  STAGE(0, 0);  // prologue: chunk 0 in flight

  int arow = wr * 16 + l15;
  for (int kc = 0; kc < 16; ++kc) {
    int cur = kc & 1;
    if (kc < 15) {
      STAGE(cur ^ 1, kc + 1);  // overwrite-safe: post-compute barrier of kc-1
      // wait chunk kc only; chunk kc+1's 3 loads REMAIN IN FLIGHT (T4)
      asm volatile("s_waitcnt vmcnt(3)" ::: "memory");
    } else {
      asm volatile("s_waitcnt vmcnt(0)" ::: "memory");
    }
    __builtin_amdgcn_s_barrier();  // raw: no compiler vmcnt(0) drain
#pragma unroll
    for (int ks = 0; ks < 2; ++ks) {
      int lb0 = ks * 8 + g * 2;
      float4 fa = *(const float4*)&xs[cur][arow * 64 + ((lb0 ^ l15) * 4)];
      float4 fb = *(const float4*)&xs[cur][arow * 64 + (((lb0 + 1) ^ l15) * 4)];
      bf16x8 a = pack8(fa, fb);
#pragma unroll
      for (int nt = 0; nt < 2; ++nt) {
        int nrow = wc * 32 + nt * 16 + l15;
        bf16x8 bb = *(const bf16x8*)
            &wss[cur][nrow * 64 + (((ks * 4 + g) ^ (l15 & 7)) * 8)];
        acc[nt] = mfma16(a, bb, acc[nt]);
      }
    }
    if (kc < 15) {
      // my LDS reads must retire before others' next STAGE overwrites
      asm volatile("s_waitcnt lgkmcnt(0)" ::: "memory");
      __builtin_amdgcn_s_barrier();
    }
  }
#undef STAGE

  // D layout: col = lane&15, row = g*4 + vv
#pragma unroll
  for (int nt = 0; nt < 2; ++nt)
#pragma unroll
    for (int vv = 0; vv < 4; ++vv) {
      int rr = r0b + wr * 16 + g * 4 + vv;
      int c = wc * 32 + nt * 16 + l15;
      float val = acc[nt][vv];
      if (mi == 0) {
        qo[(size_t)rr * 64 + c] = f2bf(val * 0.03125f);  // fold C^-0.5
      } else if (mi == 1) {
        ko[(size_t)rr * 64 + c] = f2bf(val);
      } else {
        int bb = rr >> 11, ts = rr & 2047;
        // tile-blocked vT: [b][t/32][d][t%32]
        vTb[(((size_t)bb * 64 + (ts >> 5)) * 64 + c) * 32 + (ts & 31)] =
            f2bf(val);
      }
    }

  if (mi == 2) {  // fold v column-sums into vmsum[b][d] (replaces vmean_k)
    float ps0 = acc[0][0] + acc[0][1] + acc[0][2] + acc[0][3];
    float ps1 = acc[1][0] + acc[1][1] + acc[1][2] + acc[1][3];
    __syncthreads();  // K-loop LDS fully retired; reuse xs as scratch
    float* rb = (float*)xs;  // [64 cols][16 contributors]
    rb[(wc * 32 + l15) * 16 + (wr * 4 + g)] = ps0;
    rb[(wc * 32 + 16 + l15) * 16 + (wr * 4 + g)] = ps1;
    __syncthreads();
    if (tid < 64) {
      float s = 0.f;
#pragma unroll
      for (int i = 0; i < 16; ++i) s += rb[tid * 16 + i];
      atomicAdd(&vmsum[(blockIdx.x >> 5) * 64 + tid], s);
    }
  }
}

// Flash attention: 512 threads = 8 waves = 4 key-chunks x 2 row-groups;
// 32 q-rows per block; 512 blocks (2/CU), complementary work pairing.
// T14: K/V frags for tile tt+1 issued right after tt's QK MFMAs.
__global__ __launch_bounds__(512, 4) void attn_k(
    const unsigned short* q, const unsigned short* k, const unsigned short* vTb,
    const float* vmsum, const int* lengths, float* Out) {
  __shared__ unsigned short pL[8][16][40];      // per-wave P round-trip
  __shared__ unsigned short oP[4][2][16][64];   // bf16 partial O [j][r][row][col]
  __shared__ float mP[4][2][16], lP[4][2][16];

  // complementary work pairing: co-resident blocks sum to ~constant work
  int id = blockIdx.x;
  int raw = id & 63, b = id >> 6;
  int xx = (raw + 8 * b) & 63;
  int tile = (xx < 32) ? xx : 95 - xx;   // bijective on 0..63
  int t0 = tile * 32;

  int tid = threadIdx.x;
  int w = tid >> 6, lane = tid & 63;
  int j = w >> 1, r = w & 1;
  int l15 = lane & 15, g = lane >> 4;
  int t_base = t0 + r * 16;

  const bf16x8* qrow =
      (const bf16x8*)(q + ((size_t)b * T_SEQ + t_base + l15) * 64);
  bf16x8 aq0 = qrow[g];
  bf16x8 aq1 = qrow[4 + g];

  f32x4 o[4];
  float m[4], l[4];
#pragma unroll
  for (int i = 0; i < 4; ++i) { o[i] = 0; m[i] = NEGB; l[i] = 0.f; }

  const bf16x8* kch = (const bf16x8*)k + (size_t)b * T_SEQ * 8;
  const unsigned short* vch = vTb + (size_t)b * 131072;

  // balanced contiguous tile-chunks over this block's NT key-tiles
  int NT = tile + 1;
  int qn = NT >> 2, rem = NT & 3;
  int start = j * qn + (j < rem ? j : rem);
  int end = start + qn + (j < rem ? 1 : 0);
  int capw = ((t_base + 15) >> 5) + 1;
  if (end > capw) end = capw;

  bf16x8 kb00, kb01, kb10, kb11, bv0, bv1, bv2, bv3;
  if (start < end) {  // prologue loads for first tile
    int s0 = start * 32;
    kb00 = kch[(size_t)(s0 + l15) * 8 + g];
    kb01 = kch[(size_t)(s0 + l15) * 8 + 4 + g];
    kb10 = kch[(size_t)(s0 + 16 + l15) * 8 + g];
    kb11 = kch[(size_t)(s0 + 16 + l15) * 8 + 4 + g];
    bv0 = *(const bf16x8*)&vch[((size_t)(start * 64 + l15)) * 32 + g * 8];
    bv1 = *(const bf16x8*)&vch[((size_t)(start * 64 + 16 + l15)) * 32 + g * 8];
    bv2 = *(const bf16x8*)&vch[((size_t)(start * 64 + 32 + l15)) * 32 + g * 8];
    bv3 = *(const bf16x8*)&vch[((size_t)(start * 64 + 48 + l15)) * 32 + g * 8];
  }

  for (int tt = start; tt < end; ++tt) {
    int s0 = tt * 32;
    f32x4 sa0, sa1;
    sa0 = 0; sa1 = 0;
    sa0 = mfma16(aq0, kb00, sa0);
    sa0 = mfma16(aq1, kb01, sa0);
    sa1 = mfma16(aq0, kb10, sa1);
    sa1 = mfma16(aq1, kb11, sa1);

    // T14: issue next tile's 8 loads now; softmax+PV hides their latency
    bf16x8 nk00, nk01, nk10, nk11, nv0, nv1, nv2, nv3;
    bool more = (tt + 1 < end);
    if (more) {
      int s1 = (tt + 1) * 32;
      nk00 = kch[(size_t)(s1 + l15) * 8 + g];
      nk01 = kch[(size_t)(s1 + l15) * 8 + 4 + g];
      nk10 = kch[(size_t)(s1 + 16 + l15) * 8 + g];
      nk11 = kch[(size_t)(s1 + 16 + l15) * 8 + 4 + g];
      int t1 = (tt + 1) * 64;
      nv0 = *(const bf16x8*)&vch[((size_t)(t1 + l15)) * 32 + g * 8];
      nv1 = *(const bf16x8*)&vch[((size_t)(t1 + 16 + l15)) * 32 + g * 8];
      nv2 = *(const bf16x8*)&vch[((size_t)(t1 + 32 + l15)) * 32 + g * 8];
      nv3 = *(const bf16x8*)&vch[((size_t)(t1 + 48 + l15)) * 32 + g * 8];
    }

#pragma unroll
    for (int vv = 0; vv < 4; ++vv) {
      int t = t_base + g * 4 + vv;
      float v0 = (s0 + l15 <= t) ? sa0[vv] : NEGB;
      float v1 = (s0 + 16 + l15 <= t) ? sa1[vv] : NEGB;
      float rm = fmaxf(v0, v1);
#pragma unroll
      for (int off = 8; off >= 1; off >>= 1)
        rm = fmaxf(rm, __shfl_xor(rm, off));
      float mn = fmaxf(m[vv], rm);
      float corr = __expf(m[vv] - mn);
      float p0 = (v0 == NEGB) ? 0.f : __expf(v0 - mn);  // all-masked tile guard
      float p1 = (v1 == NEGB) ? 0.f : __expf(v1 - mn);
      float rs = p0 + p1;
#pragma unroll
      for (int off = 8; off >= 1; off >>= 1) rs += __shfl_xor(rs, off);
      l[vv] = l[vv] * corr + rs;
      m[vv] = mn;
#pragma unroll
      for (int nt = 0; nt < 4; ++nt) o[nt][vv] *= corr;
      pL[w][g * 4 + vv][l15] = f2bf(p0);
      pL[w][g * 4 + vv][16 + l15] = f2bf(p1);
    }
    bf16x8 ap = *(const bf16x8*)&pL[w][l15][g * 8];
    o[0] = mfma16(ap, bv0, o[0]);
    o[1] = mfma16(ap, bv1, o[1]);
    o[2] = mfma16(ap, bv2, o[2]);
    o[3] = mfma16(ap, bv3, o[3]);
    if (more) {
      kb00 = nk00; kb01 = nk01; kb10 = nk10; kb11 = nk11;
      bv0 = nv0; bv1 = nv1; bv2 = nv2; bv3 = nv3;
    }
  }

  __syncthreads();
#pragma unroll
  for (int nt = 0; nt < 4; ++nt)
#pragma unroll
    for (int vv = 0; vv < 4; ++vv)
      oP[j][r][g * 4 + vv][nt * 16 + l15] = f2bf(o[nt][vv]);
  if (l15 == 0) {
#pragma unroll
    for (int vv = 0; vv < 4; ++vv) {
      mP[j][r][g * 4 + vv] = m[vv];
      lP[j][r][g * 4 + vv] = l[vv];
    }
  }
  __syncthreads();

  if (w < 2) {  // merge wave r=w: 16 rows x 64 cols, 4-way j-merge
    int len = lengths[b];
#pragma unroll 4
    for (int row = 0; row < 16; ++row) {
      float m0 = mP[0][w][row], m1 = mP[1][w][row];
      float m2 = mP[2][w][row], m3 = mP[3][w][row];
      float ms = fmaxf(fmaxf(m0, m1), fmaxf(m2, m3));
      float e0 = __expf(m0 - ms), e1 = __expf(m1 - ms);
      float e2 = __expf(m2 - ms), e3 = __expf(m3 - ms);
      float ls = lP[0][w][row] * e0 + lP[1][w][row] * e1 +
                 lP[2][w][row] * e2 + lP[3][w][row] * e3;
      float ov = bf2f(oP[0][w][row][lane]) * e0 +
                 bf2f(oP[1][w][row][lane]) * e1 +
                 bf2f(oP[2][w][row][lane]) * e2 +
                 bf2f(oP[3][w][row][lane]) * e3;
      float val = ov / ls;
      int t = t0 + w * 16 + row;
      if (t >= len) val = vmsum[b * 64 + lane] * (1.0f / T_SEQ);  // pad row
      Out[((size_t)b * T_SEQ + t) * 64 + lane] = val;
    }
  }
}

extern "C" void kernel_launch(void* const* d_in, const int* in_sizes, int n_in,
                              void* d_out, int out_size, void* d_ws,
                              size_t ws_size, hipStream_t stream) {
  const float* V = (const float*)d_in[0];
  const float* K = (const float*)d_in[1];
  const float* Q = (const float*)d_in[2];
  const float* Wq = (const float*)d_in[3];
  const float* Wk = (const float*)d_in[4];
  const float* Wv = (const float*)d_in[5];
  const unsigned char* mask = (const unsigned char*)d_in[6];
  float* O = (float*)d_out;
  char* ws = (char*)d_ws;

  unsigned short* wt = (unsigned short*)(ws);                        // 384 KiB
  unsigned short* qb = (unsigned short*)(ws + 393216);               // 2 MiB
  unsigned short* kb = (unsigned short*)(ws + 393216 + 2097152);     // 2 MiB
  unsigned short* vTb = (unsigned short*)(ws + 393216 + 2 * 2097152);// 2 MiB
  float* vmsum = (float*)(ws + 393216 + 3 * 2097152);                // 2 KiB
  int* lengths = (int*)(ws + 393216 + 3 * 2097152 + 2048);

  hipMemsetAsync(vmsum, 0, 512 * sizeof(float), stream);
  wt_k<<<768, 256, 0, stream>>>(Wq, Wk, Wv, wt);
  meta_k<<<NB, 256, 0, stream>>>(mask, lengths);
  proj_k<<<dim3(256, 3), 512, 0, stream>>>(Q, K, V, wt, qb, kb, vTb, vmsum);
  attn_k<<<512, 512, 0, stream>>>(qb, kb, vTb, vmsum, lengths, O);
}